// Round 2
// baseline (256.897 us; speedup 1.0000x reference)
//
#include <hip/hip_runtime.h>
#include <hip/hip_bf16.h>

#define SEQ 41
#define FEAT 128
#define KDIM 384                 // 3 * 128
#define ROWLEN (SEQ * FEAT)      // 5248 floats per batch row
#define KSTEPS (KDIM / 16)       // 24 mfma k-steps

typedef float floatx4 __attribute__((ext_vector_type(4)));
typedef float floatx16 __attribute__((ext_vector_type(16)));
typedef __bf16 bf16x8 __attribute__((ext_vector_type(8)));
typedef unsigned short ushortx8 __attribute__((ext_vector_type(8)));

// fp32 -> bf16 bits, round-to-nearest-even (inputs are finite normals)
__device__ __forceinline__ unsigned short f2bf(float f) {
    unsigned int u = __builtin_bit_cast(unsigned int, f);
    unsigned int r = (u + 0x7fffu + ((u >> 16) & 1u)) >> 16;
    return (unsigned short)r;
}

__device__ __forceinline__ bf16x8 cvt8(floatx4 lo, floatx4 hi) {
    ushortx8 u;
#pragma unroll
    for (int j = 0; j < 4; j++) { u[j] = f2bf(lo[j]); u[4 + j] = f2bf(hi[j]); }
    return __builtin_bit_cast(bf16x8, u);
}

// ---------------- prepass: W (s, k, n) fp32 -> Wt (s, n, k) bf16 ----------------
__global__ __launch_bounds__(256) void wt_kernel(const float* __restrict__ W,
                                                 unsigned short* __restrict__ Wt) {
    int t = blockIdx.x * 256 + threadIdx.x;           // 41*128*48 total
    int n  = t & (FEAT - 1);
    int r  = t >> 7;
    int k0 = (r % (KDIM / 8)) * 8;
    int s  = r / (KDIM / 8);
    const float* Ws = W + (size_t)s * KDIM * FEAT;
    ushortx8 v;
#pragma unroll
    for (int j = 0; j < 8; j++) v[j] = f2bf(Ws[(size_t)(k0 + j) * FEAT + n]);
    *reinterpret_cast<ushortx8*>(Wt + ((size_t)(s * FEAT + n)) * KDIM + k0) = v;
}

// ---------------- LDS-free register GEMM ----------------
// Wave computes 32(m) x 128(n); block = 4 waves = 128 rows, full N=128, K=384.
// A fragments loaded straight from X (contiguous window), B from Wt (L2-resident).
template <int USE_WT>
__global__ __launch_bounds__(256) void gemm_kernel(const float* __restrict__ X,
                                                   const void* __restrict__ Wsrc,
                                                   const float* __restrict__ bias,
                                                   float* __restrict__ out) {
    const int tid  = threadIdx.x;
    const int lane = tid & 63;
    const int wv   = tid >> 6;
    const int s    = blockIdx.x;         // s-fastest: X window overlap stays hot in L2
    const int mblk = blockIdx.y;
    const int nl   = lane & 31;          // A: row-within-tile / B,C: col-within-tile
    const int kh   = lane >> 5;          // k-half (8 elems each)

    const int row = mblk * 128 + wv * 32 + nl;
    const float* xrow = X + (size_t)row * ROWLEN;
    const int obase = (s - 1) * FEAT + kh * 8;   // window offset, may be <0 / >=ROWLEN

    const unsigned short* Wt = (const unsigned short*)Wsrc;
    const float* Wf = (const float*)Wsrc;

    floatx16 acc[4];
#pragma unroll
    for (int nt = 0; nt < 4; nt++) acc[nt] = (floatx16)(0.f);

    floatx4 a_lo, a_hi;
    ushortx8 bq[4];

#define LOAD_A(ks)                                                        \
    {                                                                     \
        int o = obase + (ks) * 16;                                        \
        a_lo = (floatx4)(0.f); a_hi = (floatx4)(0.f);                     \
        if (o >= 0 && o < ROWLEN) {                                       \
            a_lo = *reinterpret_cast<const floatx4*>(xrow + o);           \
            a_hi = *reinterpret_cast<const floatx4*>(xrow + o + 4);       \
        }                                                                 \
    }
#define LOAD_B(ks)                                                              \
    if (USE_WT) {                                                               \
        _Pragma("unroll")                                                       \
        for (int nt = 0; nt < 4; nt++)                                          \
            bq[nt] = *reinterpret_cast<const ushortx8*>(                        \
                Wt + ((size_t)(s * FEAT + nt * 32 + nl)) * KDIM + (ks) * 16 + kh * 8); \
    } else {                                                                    \
        _Pragma("unroll")                                                       \
        for (int nt = 0; nt < 4; nt++) {                                        \
            _Pragma("unroll")                                                   \
            for (int j = 0; j < 8; j++)                                         \
                bq[nt][j] = f2bf(Wf[((size_t)s * KDIM + (ks) * 16 + kh * 8 + j) * FEAT \
                                    + nt * 32 + nl]);                           \
        }                                                                       \
    }

    LOAD_A(0);
    LOAD_B(0);

#pragma unroll 4
    for (int ks = 0; ks < KSTEPS; ks++) {
        bf16x8 av = cvt8(a_lo, a_hi);
        bf16x8 bv0 = __builtin_bit_cast(bf16x8, bq[0]);
        bf16x8 bv1 = __builtin_bit_cast(bf16x8, bq[1]);
        bf16x8 bv2 = __builtin_bit_cast(bf16x8, bq[2]);
        bf16x8 bv3 = __builtin_bit_cast(bf16x8, bq[3]);
        if (ks + 1 < KSTEPS) {           // register prefetch of next k-step
            LOAD_A(ks + 1);
            LOAD_B(ks + 1);
        }
        acc[0] = __builtin_amdgcn_mfma_f32_32x32x16_bf16(av, bv0, acc[0], 0, 0, 0);
        acc[1] = __builtin_amdgcn_mfma_f32_32x32x16_bf16(av, bv1, acc[1], 0, 0, 0);
        acc[2] = __builtin_amdgcn_mfma_f32_32x32x16_bf16(av, bv2, acc[2], 0, 0, 0);
        acc[3] = __builtin_amdgcn_mfma_f32_32x32x16_bf16(av, bv3, acc[3], 0, 0, 0);
    }

    // epilogue: bias + relu; C layout: col(n)=lane&31, row(m)=(r&3)+8*(r>>2)+4*kh
    const int mbase = mblk * 128 + wv * 32 + 4 * kh;
#pragma unroll
    for (int nt = 0; nt < 4; nt++) {
        int n = nt * 32 + nl;
        float bv = bias[s * FEAT + n];
#pragma unroll
        for (int r = 0; r < 16; r++) {
            int m = mbase + (r & 3) + 8 * (r >> 2);
            float v = acc[nt][r] + bv;
            v = v > 0.f ? v : 0.f;
            out[((size_t)m * SEQ + s) * FEAT + n] = v;
        }
    }
#undef LOAD_A
#undef LOAD_B
}

extern "C" void kernel_launch(void* const* d_in, const int* in_sizes, int n_in,
                              void* d_out, int out_size, void* d_ws, size_t ws_size,
                              hipStream_t stream) {
    const float* X    = (const float*)d_in[0];
    const float* W    = (const float*)d_in[1];
    const float* bias = (const float*)d_in[2];
    float* out = (float*)d_out;

    const int B = in_sizes[0] / ROWLEN;               // 4096
    dim3 grid(SEQ, B / 128);

    const size_t wt_bytes = (size_t)SEQ * FEAT * KDIM * sizeof(unsigned short);
    if (ws_size >= wt_bytes) {
        unsigned short* Wt = (unsigned short*)d_ws;
        wt_kernel<<<(SEQ * FEAT * (KDIM / 8) + 255) / 256, 256, 0, stream>>>(W, Wt);
        gemm_kernel<1><<<grid, 256, 0, stream>>>(X, (const void*)Wt, bias, out);
    } else {
        gemm_kernel<0><<<grid, 256, 0, stream>>>(X, (const void*)W, bias, out);
    }
}

// Round 3
// 184.181 us; speedup vs baseline: 1.3948x; 1.3948x over previous
//
#include <hip/hip_runtime.h>

#define SEQ 41
#define FEAT 128
#define KDIM 384
#define ROWLEN (SEQ * FEAT)        // 5248 floats per batch row
#define BM 128

typedef float floatx4 __attribute__((ext_vector_type(4)));
typedef __bf16 bf16x8 __attribute__((ext_vector_type(8)));
typedef unsigned short ushortx4 __attribute__((ext_vector_type(4)));
typedef unsigned short ushortx8 __attribute__((ext_vector_type(8)));

// fp32 -> bf16 bits, round-to-nearest-even
__device__ __forceinline__ unsigned short f2bf(float f) {
    unsigned int u = __builtin_bit_cast(unsigned int, f);
    return (unsigned short)((u + 0x7fffu + ((u >> 16) & 1u)) >> 16);
}

// async global->LDS DMA, 16 B per lane, LDS dest = uniform base + lane*16
#define DMA16(g, l)                                                          \
    __builtin_amdgcn_global_load_lds(                                        \
        (const __attribute__((address_space(1))) void*)(g),                  \
        (__attribute__((address_space(3))) void*)(l), 16, 0, 0)

// ---------------- prepass: W[s][k][n] fp32 -> Wt2 in MFMA fragment order --------
// Wt2 linear layout: [s][slab(6)][ks(2)][nt(8)][lane(64)][8 bf16]
//   n = nt*16 + (lane&15);  k = slab*64 + ks*32 + (lane>>4)*8 + j
// One thread produces one 16 B lane-slot (coalesced stores; strided reads are L2-hit).
__global__ __launch_bounds__(256) void wt2_kernel(const float* __restrict__ W,
                                                  unsigned short* __restrict__ Wt2) {
    int t = blockIdx.x * 256 + threadIdx.x;   // exactly 41*6144 threads
    int s = t / 6144, g = t % 6144;
    int lane = g & 63, nt = (g >> 6) & 7, ks = (g >> 9) & 1, slab = g >> 10;
    int n  = nt * 16 + (lane & 15);
    int k0 = slab * 64 + ks * 32 + (lane >> 4) * 8;
    const float* Ws = W + (size_t)s * KDIM * FEAT;
    ushortx8 v;
#pragma unroll
    for (int j = 0; j < 8; j++) v[j] = f2bf(Ws[(size_t)(k0 + j) * FEAT + n]);
    *reinterpret_cast<ushortx8*>(Wt2 + (size_t)t * 8) = v;
}

// ---------------- main GEMM ----------------
// Block: 256 thr = 4 waves (2x2), tile BM=128 x N=128, BK=64, double-buffered.
// All LDS in fragment order: [buf][ks][tile16][lane*8 bf16]  (reads = uniform+lane*16).
template <int USE_WT>
__global__ __launch_bounds__(256, 2) void gemm_kernel(const float* __restrict__ X,
                                                      const void* __restrict__ Wsrc,
                                                      const float* __restrict__ bias,
                                                      float* __restrict__ out) {
    __shared__ unsigned short Afrag[2][2][8][512];   // 32 KB
    __shared__ unsigned short Bfrag[2][2][8][512];   // 32 KB

    const int tid  = threadIdx.x;
    const int lane = tid & 63;
    const int wv   = tid >> 6;
    const int s    = blockIdx.y;
    const int m0   = blockIdx.x * BM;

    // OOB window cols form whole BK=64 slabs -> restrict K-loop, no bounds checks
    const int klo = (s == 0) ? 2 : 0;
    const int khi = (s == SEQ - 1) ? 4 : 6;
    const int nk  = khi - klo;
    const int obase = (s - 1) * FEAT;

    const int colq = lane & 15, quad = lane >> 4;
    const int wr = wv >> 1, wc = wv & 1;

    // A staging thread constants: 8 lanes per row, 2x16B contiguous loads
    const int ar = tid >> 3;          // row 0..31 (+pass*32)
    const int ag = tid & 7;
    const int aq = ag >> 1, ahalf = ag & 1;   // frag quad / half for this thread's 4 cols

    const unsigned short* Wt2 = (const unsigned short*)Wsrc;
    const float* Wf = (const float*)Wsrc;

    floatx4 acc[4][4];
#pragma unroll
    for (int i = 0; i < 4; i++)
#pragma unroll
        for (int j = 0; j < 4; j++) acc[i][j] = (floatx4){0.f, 0.f, 0.f, 0.f};

    floatx4 a0[4], a1[4];

    auto stageA_load = [&](int kki) {
#pragma unroll
        for (int p = 0; p < 4; p++) {
            const float* base = X + (size_t)(m0 + p * 32 + ar) * ROWLEN
                                  + obase + kki * 64 + ag * 4;
            a0[p] = *reinterpret_cast<const floatx4*>(base);
            a1[p] = *reinterpret_cast<const floatx4*>(base + 32);
        }
    };
    auto stageA_write = [&](int buf) {
#pragma unroll
        for (int p = 0; p < 4; p++) {
            int r  = p * 32 + ar;
            int mt = r >> 4;
            int sl = ((r & 15) + 16 * aq) * 8 + ahalf * 4;
            ushortx4 w0, w1;
#pragma unroll
            for (int e = 0; e < 4; e++) { w0[e] = f2bf(a0[p][e]); w1[e] = f2bf(a1[p][e]); }
            *reinterpret_cast<ushortx4*>(&Afrag[buf][0][mt][sl]) = w0;
            *reinterpret_cast<ushortx4*>(&Afrag[buf][1][mt][sl]) = w1;
        }
    };
    auto stageB = [&](int buf, int kki) {
        if (USE_WT) {
            const unsigned short* src = Wt2 + (size_t)(s * 6 + kki) * 8192;
#pragma unroll
            for (int j = 0; j < 4; j++) {
                int fid = wv * 4 + j;                       // 16 fragments / 4 waves
                const unsigned short* g = src + fid * 512 + lane * 8;
                DMA16(g, &Bfrag[buf][fid >> 3][fid & 7][0]);
            }
        } else {
            // fallback: stage from fp32 W[s][k][n] (uncoalesced, correctness path)
#pragma unroll
            for (int p = 0; p < 4; p++) {
                int g2 = p * 256 + tid;
                int ln = g2 & 63, nt = (g2 >> 6) & 7, ks = (g2 >> 9) & 1;
                int n = nt * 16 + (ln & 15);
                int k = kki * 64 + ks * 32 + (ln >> 4) * 8;
                ushortx8 v;
#pragma unroll
                for (int j = 0; j < 8; j++)
                    v[j] = f2bf(Wf[((size_t)s * KDIM + k + j) * FEAT + n]);
                *reinterpret_cast<ushortx8*>(&Bfrag[buf][ks][nt][ln * 8]) = v;
            }
        }
    };
    auto compute = [&](int buf) {
#pragma unroll
        for (int ks = 0; ks < 2; ks++) {
            bf16x8 af[4], bf[4];
#pragma unroll
            for (int i = 0; i < 4; i++)
                af[i] = *reinterpret_cast<const bf16x8*>(&Afrag[buf][ks][wr * 4 + i][lane * 8]);
#pragma unroll
            for (int i = 0; i < 4; i++)
                bf[i] = *reinterpret_cast<const bf16x8*>(&Bfrag[buf][ks][wc * 4 + i][lane * 8]);
#pragma unroll
            for (int mi = 0; mi < 4; mi++)
#pragma unroll
                for (int ni = 0; ni < 4; ni++)
                    acc[mi][ni] = __builtin_amdgcn_mfma_f32_16x16x32_bf16(
                        af[mi], bf[ni], acc[mi][ni], 0, 0, 0);
        }
    };

    // prologue: stage buffer 0
    stageA_load(klo);
    stageB(0, klo);
    stageA_write(0);

    for (int i = 0; i < nk; i++) {
        __syncthreads();                       // drains DMA (vmcnt) + LDS writes (lgkm)
        int cur = i & 1, nxt = cur ^ 1;
        if (i + 1 < nk) {
            stageA_load(klo + i + 1);          // issue global loads (regs)
            stageB(nxt, klo + i + 1);          // issue async DMA
        }
        compute(cur);                          // MFMAs shadow the load latency
        if (i + 1 < nk) stageA_write(nxt);     // cvt + LDS write after compute
    }

    // epilogue: bias + relu; C layout (verified r1): col=lane&15, row=quad*4+reg
#pragma unroll
    for (int mi = 0; mi < 4; mi++) {
        int m = m0 + (wr * 4 + mi) * 16 + quad * 4;
#pragma unroll
        for (int ni = 0; ni < 4; ni++) {
            int n = (wc * 4 + ni) * 16 + colq;
            float bv = bias[s * FEAT + n];
#pragma unroll
            for (int r = 0; r < 4; r++) {
                float v = acc[mi][ni][r] + bv;
                v = v > 0.f ? v : 0.f;
                out[((size_t)(m + r) * SEQ + s) * FEAT + n] = v;
            }
        }
    }
}

extern "C" void kernel_launch(void* const* d_in, const int* in_sizes, int n_in,
                              void* d_out, int out_size, void* d_ws, size_t ws_size,
                              hipStream_t stream) {
    const float* X    = (const float*)d_in[0];
    const float* W    = (const float*)d_in[1];
    const float* bias = (const float*)d_in[2];
    float* out = (float*)d_out;

    const int B = in_sizes[0] / ROWLEN;               // 4096
    dim3 grid(B / BM, SEQ);

    const size_t wt_bytes = (size_t)SEQ * 6 * 8192 * sizeof(unsigned short);  // ~4 MB
    if (ws_size >= wt_bytes) {
        unsigned short* Wt2 = (unsigned short*)d_ws;
        wt2_kernel<<<(SEQ * 6144) / 256, 256, 0, stream>>>(W, Wt2);
        gemm_kernel<1><<<grid, 256, 0, stream>>>(X, (const void*)Wt2, bias, out);
    } else {
        gemm_kernel<0><<<grid, 256, 0, stream>>>(X, (const void*)W, bias, out);
    }
}